// Round 3
// baseline (2205.352 us; speedup 1.0000x reference)
//
#include <hip/hip_runtime.h>

#define Bb 64
#define Nn 128
#define Ee 2048
#define Hh 256
#define Ll 6
#define TN 8192
#define TE 131072
#define EDGE 50
#define EKPAD 64

typedef __attribute__((ext_vector_type(4))) float f32x4;
typedef __attribute__((ext_vector_type(8))) __bf16 bf16x8;

__device__ inline float b2f(unsigned short u) {
    union { unsigned u; float f; } v; v.u = ((unsigned)u) << 16; return v.f;
}
__device__ inline unsigned short f2b(float f) {
    union { float f; unsigned u; } v; v.f = f;
    unsigned r = v.u + 0x7fffu + ((v.u >> 16) & 1u);
    return (unsigned short)(r >> 16);
}
__device__ inline float spf(float x) {   // softplus, stable
    return fmaxf(x, 0.f) + log1pf(expf(-fabsf(x)));
}
__device__ inline float sspf(float x) {  // shifted softplus
    return spf(x) - 0.69314718055994530942f;
}

// ================= fused 2-layer MLP =================
// out = [ssp(A @ W1T^T + b1)] @ W2T^T + b2     (second act: none)
// A: M x K1 bf16.  W1T: 256 x K1 bf16.  W2T: 256 x 256 bf16.
// Block: 128 rows. GEMM1 computed SWAPPED (D[c][e]) so lanes hold contiguous
// channel runs -> packed 8B ds_writes of t into a 16B-XOR-swizzled LDS tile.
// GEMM2 reads t from LDS; W2 frags straight from global (L2-hot).
// OUTMODE 0: Cb = bf16 result. 2: Xf += result; Xb = bf16(Xf).
template <int K1, int OUTMODE>
__global__ __launch_bounds__(256, 2)
void fused_mlp(const unsigned short* __restrict__ A,
               const unsigned short* __restrict__ W1T,
               const float* __restrict__ b1,
               const unsigned short* __restrict__ W2T,
               const float* __restrict__ b2,
               unsigned short* __restrict__ Cb,
               float* __restrict__ Xf,
               unsigned short* __restrict__ Xb)
{
    __shared__ __align__(16) unsigned char t_lds[128 * 512];   // 64KB

    const int tid  = threadIdx.x;
    const int lane = tid & 63;
    const int w    = tid >> 6;
    const int r16  = lane & 15;
    const int kg   = lane >> 4;
    const long brow = (long)blockIdx.x * 128;

    // ---------- GEMM1 (swapped): D[c][e], wave w owns e in [w*32, w*32+32) ----------
    f32x4 acc1[16][2];
#pragma unroll
    for (int cf = 0; cf < 16; ++cf) {
        acc1[cf][0] = f32x4{0.f, 0.f, 0.f, 0.f};
        acc1[cf][1] = f32x4{0.f, 0.f, 0.f, 0.f};
    }
#pragma unroll
    for (int kk = 0; kk < K1 / 32; ++kk) {
        bf16x8 be[2];
#pragma unroll
        for (int eh = 0; eh < 2; ++eh) {
            const long erow = brow + w * 32 + eh * 16 + r16;
            be[eh] = *(const bf16x8*)(A + erow * K1 + kk * 32 + kg * 8);
        }
#pragma unroll
        for (int cf = 0; cf < 16; ++cf) {
            bf16x8 aw = *(const bf16x8*)(W1T + (cf * 16 + r16) * K1 + kk * 32 + kg * 8);
            acc1[cf][0] = __builtin_amdgcn_mfma_f32_16x16x32_bf16(aw, be[0], acc1[cf][0], 0, 0, 0);
            acc1[cf][1] = __builtin_amdgcn_mfma_f32_16x16x32_bf16(aw, be[1], acc1[cf][1], 0, 0, 0);
        }
    }

    // bias + ssp + pack(4 x bf16 = 8B) + swizzled LDS write
#pragma unroll
    for (int cf = 0; cf < 16; ++cf) {
        const int c0 = cf * 16 + kg * 4;
        const f32x4 bv = *(const f32x4*)(b1 + c0);
#pragma unroll
        for (int eh = 0; eh < 2; ++eh) {
            float v0 = sspf(acc1[cf][eh][0] + bv[0]);
            float v1 = sspf(acc1[cf][eh][1] + bv[1]);
            float v2 = sspf(acc1[cf][eh][2] + bv[2]);
            float v3 = sspf(acc1[cf][eh][3] + bv[3]);
            uint2 p;
            p.x = (unsigned)f2b(v0) | ((unsigned)f2b(v1) << 16);
            p.y = (unsigned)f2b(v2) | ((unsigned)f2b(v3) << 16);
            const int e = w * 32 + eh * 16 + r16;           // local row 0..127
            const int off = (e * 512 + c0 * 2) ^ ((e & 7) << 4);
            *(uint2*)(t_lds + off) = p;
        }
    }
    __syncthreads();

    // ---------- GEMM2: out[e][n] = sum_c t[e][c] * W2T[n][c] ----------
    const int wr = w >> 1, wc = w & 1;    // wave: 64 rows x 128 cols
    f32x4 acc2[4][8];
#pragma unroll
    for (int m = 0; m < 4; ++m)
#pragma unroll
        for (int n = 0; n < 8; ++n) acc2[m][n] = f32x4{0.f, 0.f, 0.f, 0.f};

#pragma unroll
    for (int kk = 0; kk < 8; ++kk) {
        bf16x8 af[4], bw[8];
#pragma unroll
        for (int m = 0; m < 4; ++m) {
            const int row = wr * 64 + m * 16 + r16;
            const int off = (row * 512 + (kk * 4 + kg) * 16) ^ ((row & 7) << 4);
            af[m] = *(const bf16x8*)(t_lds + off);
        }
#pragma unroll
        for (int n = 0; n < 8; ++n) {
            const int col = wc * 128 + n * 16 + r16;
            bw[n] = *(const bf16x8*)(W2T + col * 256 + kk * 32 + kg * 8);
        }
#pragma unroll
        for (int m = 0; m < 4; ++m)
#pragma unroll
            for (int n = 0; n < 8; ++n)
                acc2[m][n] = __builtin_amdgcn_mfma_f32_16x16x32_bf16(af[m], bw[n], acc2[m][n], 0, 0, 0);
    }

    // epilogue (verified C/D layout: row = kg*4+j, col = r16)
#pragma unroll
    for (int m = 0; m < 4; ++m) {
#pragma unroll
        for (int n = 0; n < 8; ++n) {
            const int col = wc * 128 + n * 16 + r16;
            const float bv = b2[col];
#pragma unroll
            for (int j = 0; j < 4; ++j) {
                const long row = brow + wr * 64 + m * 16 + kg * 4 + j;
                const long idx = row * 256 + col;
                float v = acc2[m][n][j] + bv;
                if (OUTMODE == 0) {
                    Cb[idx] = f2b(v);
                } else {
                    float nx = Xf[idx] + v;
                    Xf[idx] = nx;
                    Xb[idx] = f2b(nx);
                }
            }
        }
    }
}

// ---------------- GEMM (kept for readout layer 1) ----------------
template <int ACT, int OUTMODE, int TM>
__global__ __launch_bounds__(256)
void gemm_k(const unsigned short* __restrict__ A,
            const unsigned short* __restrict__ WT,
            const float* __restrict__ bias,
            unsigned short* __restrict__ Cb,
            float* __restrict__ Xf,
            unsigned short* __restrict__ Xb,
            int M, int N, int K)
{
    constexpr int BK = 64;
    constexpr int TNc = 128;
    constexpr int MR = TM / 32;
    constexpr int NR = 4;

    __shared__ unsigned short As[TM * BK];
    __shared__ unsigned short Bs[TNc * BK];

    const int tid  = threadIdx.x;
    const int lane = tid & 63;
    const int w    = tid >> 6;
    const int wr   = w >> 1, wc = w & 1;
    const int r16  = lane & 15;
    const int kg   = lane >> 4;

    const long brow = (long)blockIdx.y * TM;
    const int  bcol = blockIdx.x * TNc;

    constexpr int ACH = TM / 8;
    constexpr int NCH = ACH + TNc / 8;
    constexpr int IPW = NCH / 4;
    const int lrow  = lane >> 3;
    const int lslot = lane & 7;

    f32x4 acc[MR][NR];
#pragma unroll
    for (int m = 0; m < MR; ++m)
#pragma unroll
        for (int n = 0; n < NR; ++n) acc[m][n] = f32x4{0.f, 0.f, 0.f, 0.f};

    for (int k0 = 0; k0 < K; k0 += BK) {
        __syncthreads();
#pragma unroll
        for (int i = 0; i < IPW; ++i) {
            const int c    = w * IPW + i;
            const bool isA = c < ACH;
            const int cc   = isA ? c : c - ACH;
            const int srow = cc * 8 + lrow;
            const int kch  = lslot ^ (srow & 7);
            const unsigned short* gp = isA
                ? A  + (brow + srow) * (long)K + k0 + kch * 8
                : WT + (bcol + srow) * (long)K + k0 + kch * 8;
            unsigned short* lp = (isA ? As : Bs) + cc * 512;
            __builtin_amdgcn_global_load_lds(
                (const __attribute__((address_space(1))) void*)gp,
                (__attribute__((address_space(3))) void*)lp, 16, 0, 0);
        }
        __syncthreads();

        bf16x8 a[MR][2], b[NR][2];
#pragma unroll
        for (int m = 0; m < MR; ++m) {
            const int row = wr * (MR * 16) + m * 16 + r16;
            const unsigned short* base = As + row * BK;
#pragma unroll
            for (int kk = 0; kk < 2; ++kk) {
                const int slot = (kk * 4 + kg) ^ (row & 7);
                a[m][kk] = *(const bf16x8*)(base + slot * 8);
            }
        }
#pragma unroll
        for (int n = 0; n < NR; ++n) {
            const int row = wc * 64 + n * 16 + r16;
            const unsigned short* base = Bs + row * BK;
#pragma unroll
            for (int kk = 0; kk < 2; ++kk) {
                const int slot = (kk * 4 + kg) ^ (row & 7);
                b[n][kk] = *(const bf16x8*)(base + slot * 8);
            }
        }
#pragma unroll
        for (int kk = 0; kk < 2; ++kk)
#pragma unroll
            for (int m = 0; m < MR; ++m)
#pragma unroll
                for (int n = 0; n < NR; ++n)
                    acc[m][n] = __builtin_amdgcn_mfma_f32_16x16x32_bf16(
                        a[m][kk], b[n][kk], acc[m][n], 0, 0, 0);
    }

#pragma unroll
    for (int m = 0; m < MR; ++m) {
#pragma unroll
        for (int n = 0; n < NR; ++n) {
            const int col = bcol + wc * 64 + n * 16 + r16;
            const float bv = bias[col];
#pragma unroll
            for (int j = 0; j < 4; ++j) {
                const long row = brow + wr * (MR * 16) + m * 16 + kg * 4 + j;
                float v = acc[m][n][j] + bv;
                if (ACT) v = sspf(v);
                const long idx = row * (long)N + col;
                if (OUTMODE == 0) {
                    Cb[idx] = f2b(v);
                } else {
                    float nx = Xf[idx] + v;
                    Xf[idx] = nx;
                    Xb[idx] = f2b(nx);
                }
            }
        }
    }
}

// ---------------- small kernels ----------------
__global__ void k_offsets(const int* __restrict__ num_nodes, int* __restrict__ off) {
    __shared__ int s[Bb];
    int t = threadIdx.x;
    s[t] = num_nodes[t];
    __syncthreads();
    for (int d = 1; d < Bb; d <<= 1) {
        int v = (t >= d) ? s[t - d] : 0;
        __syncthreads();
        s[t] += v;
        __syncthreads();
    }
    off[t + 1] = s[t];
    if (t == 0) off[0] = 0;
}

__global__ void k_edgeprep(const int* __restrict__ edges, const int* __restrict__ off,
                           int* __restrict__ gsrc, int* __restrict__ gdst, int* __restrict__ cnt) {
    int ge = blockIdx.x * 256 + threadIdx.x;
    if (ge >= TE) return;
    int b = ge >> 11;
    int o = off[b];
    gsrc[ge] = edges[ge * 2 + 0] + o;
    int d = edges[ge * 2 + 1] + o;
    gdst[ge] = d;
    atomicAdd(&cnt[d], 1);
}

__global__ void k_scan(const int* __restrict__ cnt, int* __restrict__ coff, int* __restrict__ pos) {
    __shared__ int part[1024];
    int t = threadIdx.x;
    int loc[8];
    int s = 0;
#pragma unroll
    for (int j = 0; j < 8; ++j) { loc[j] = cnt[t * 8 + j]; s += loc[j]; }
    part[t] = s;
    __syncthreads();
    for (int d = 1; d < 1024; d <<= 1) {
        int v = (t >= d) ? part[t - d] : 0;
        __syncthreads();
        part[t] += v;
        __syncthreads();
    }
    int base = part[t] - s;
#pragma unroll
    for (int j = 0; j < 8; ++j) {
        int idx = t * 8 + j;
        coff[idx] = base;
        pos[idx]  = base;
        base += loc[j];
    }
    if (t == 1023) coff[TN] = part[1023];
}

__global__ void k_fill(const int* __restrict__ gdst, const int* __restrict__ gsrc,
                       int* __restrict__ pos, int* __restrict__ eidl, int* __restrict__ gsrcs) {
    int ge = blockIdx.x * 256 + threadIdx.x;
    if (ge >= TE) return;
    int p = atomicAdd(&pos[gdst[ge]], 1);
    eidl[p]  = ge;
    gsrcs[p] = gsrc[ge];
}

__global__ void k_rbf(const float* __restrict__ ef, unsigned short* __restrict__ erbf) {
    int gid = blockIdx.x * 256 + threadIdx.x;
    int ge = gid >> 6, k = gid & 63;
    float v = 0.f;
    if (k < EDGE) {
        float d = ef[ge];
        float t = d - 0.1f * (float)k;
        v = expf(-50.f * t * t);
    }
    erbf[gid] = f2b(v);
}

__global__ void k_embed(const int* __restrict__ nodes, const float* __restrict__ embed,
                        float* __restrict__ x, unsigned short* __restrict__ xb) {
    int gid = blockIdx.x * 256 + threadIdx.x;
    int i = gid >> 8, c = gid & 255;
    float v = embed[(nodes[i] << 8) + c];
    x[gid] = v;
    xb[gid] = f2b(v);
}

__global__ void k_wprep(const float* __restrict__ me_w1, const float* __restrict__ me_w2,
                        const float* __restrict__ mn_w1, const float* __restrict__ mn_w2,
                        const float* __restrict__ st_w1, const float* __restrict__ st_w2,
                        const float* __restrict__ ro_w1,
                        unsigned short* __restrict__ me1T, unsigned short* __restrict__ me2T,
                        unsigned short* __restrict__ mn1T, unsigned short* __restrict__ mn2T,
                        unsigned short* __restrict__ st1T, unsigned short* __restrict__ st2T,
                        unsigned short* __restrict__ ro1T) {
    int gid = blockIdx.x * 256 + threadIdx.x;
    const int S1 = Ll * 256 * EKPAD;
    if (gid < S1) {
        int i = gid / (256 * EKPAD);
        int r = gid % (256 * EKPAD);
        int n = r / EKPAD, k = r % EKPAD;
        float v = (k < EDGE) ? me_w1[(i * EDGE + k) * 256 + n] : 0.f;
        me1T[gid] = f2b(v);
        return;
    }
    gid -= S1;
    const int S2 = Ll * 256 * 256;
    const float* srcs[5] = { me_w2, mn_w1, mn_w2, st_w1, st_w2 };
    unsigned short* dsts[5] = { me2T, mn1T, mn2T, st1T, st2T };
#pragma unroll
    for (int q = 0; q < 5; ++q) {
        if (gid < S2) {
            int i = gid >> 16;
            int r = gid & 65535;
            int n = r >> 8, k = r & 255;
            dsts[q][gid] = f2b(srcs[q][(i << 16) + k * 256 + n]);
            return;
        }
        gid -= S2;
    }
    int n = gid >> 8, k = gid & 255;
    ro1T[gid] = f2b(ro_w1[k * 256 + n]);
}

__global__ void k_agg(const unsigned short* __restrict__ nmsgb, const unsigned short* __restrict__ gates,
                      const int* __restrict__ coff, const int* __restrict__ gsrcs,
                      const int* __restrict__ eidl, unsigned short* __restrict__ msum) {
    int n = blockIdx.x, c = threadIdx.x;
    float s = 0.f;
    int beg = coff[n], end = coff[n + 1];
    for (int i = beg; i < end; ++i) {
        int e  = eidl[i];
        int sr = gsrcs[i];
        s += b2f(nmsgb[(sr << 8) + c]) * b2f(gates[(e << 8) + c]);
    }
    msum[(n << 8) + c] = f2b(s);
}

__global__ void k_readout(const unsigned short* __restrict__ t, const float* __restrict__ w2,
                          const float* __restrict__ b2, const int* __restrict__ num_nodes,
                          const float* __restrict__ evw, const float* __restrict__ evb,
                          float* __restrict__ out) {
    __shared__ float red[256];
    int b = blockIdx.x, tid = threadIdx.x;
    const unsigned short* tb = t + (long)b * Nn * 256;
    float part = 0.f;
    for (int i = tid; i < Nn * 256; i += 256)
        part += b2f(tb[i]) * w2[i & 255];
    red[tid] = part;
    __syncthreads();
    for (int d = 128; d > 0; d >>= 1) {
        if (tid < d) red[tid] += red[tid + d];
        __syncthreads();
    }
    if (tid == 0) {
        float g = red[0] + (float)Nn * b2[0];
        g = g * 2.0f + (-1.5f) * (float)num_nodes[b];
        out[b * 4 + 0] = g * evw[0] + evb[0];
        out[b * 4 + 1] = spf(g * evw[1] + evb[1]);
        out[b * 4 + 2] = spf(g * evw[2] + evb[2]) + 1.f;
        out[b * 4 + 3] = spf(g * evw[3] + evb[3]);
    }
}

// ---------------- workspace layout ----------------
constexpr size_t al(size_t x) { return (x + 255) & ~(size_t)255; }
constexpr size_t O_OFF   = 0;
constexpr size_t O_GSRC  = al(O_OFF + 65 * 4);
constexpr size_t O_GDST  = al(O_GSRC + (size_t)TE * 4);
constexpr size_t O_CNT   = al(O_GDST + (size_t)TE * 4);
constexpr size_t O_COFF  = al(O_CNT + (size_t)TN * 4);
constexpr size_t O_POS   = al(O_COFF + (size_t)(TN + 1) * 4);
constexpr size_t O_EIDL  = al(O_POS + (size_t)TN * 4);
constexpr size_t O_GSRCS = al(O_EIDL + (size_t)TE * 4);
constexpr size_t O_ERBF  = al(O_GSRCS + (size_t)TE * 4);
constexpr size_t O_ME1T  = al(O_ERBF + (size_t)TE * EKPAD * 2);
constexpr size_t O_ME2T  = al(O_ME1T + (size_t)Ll * 256 * EKPAD * 2);
constexpr size_t O_MN1T  = al(O_ME2T + (size_t)Ll * 256 * 256 * 2);
constexpr size_t O_MN2T  = al(O_MN1T + (size_t)Ll * 256 * 256 * 2);
constexpr size_t O_ST1T  = al(O_MN2T + (size_t)Ll * 256 * 256 * 2);
constexpr size_t O_ST2T  = al(O_ST1T + (size_t)Ll * 256 * 256 * 2);
constexpr size_t O_RO1T  = al(O_ST2T + (size_t)Ll * 256 * 256 * 2);
constexpr size_t O_X     = al(O_RO1T + (size_t)256 * 256 * 2);
constexpr size_t O_XB    = al(O_X + (size_t)TN * 256 * 4);
constexpr size_t O_TMPB  = al(O_XB + (size_t)TN * 256 * 2);
constexpr size_t O_NMSG  = al(O_TMPB + (size_t)TN * 256 * 2);
constexpr size_t O_MSUM  = al(O_NMSG + (size_t)TN * 256 * 2);
constexpr size_t O_TEDG  = al(O_MSUM + (size_t)TN * 256 * 2);
constexpr size_t O_GATE  = al(O_TEDG + (size_t)TE * 256 * 2);
constexpr size_t WS_NEED = al(O_GATE + (size_t)TE * 256 * 2);

extern "C" void kernel_launch(void* const* d_in, const int* in_sizes, int n_in,
                              void* d_out, int out_size, void* d_ws, size_t ws_size,
                              hipStream_t stream) {
    if (ws_size < WS_NEED) return;

    const int*   nodes     = (const int*)d_in[0];
    const int*   num_nodes = (const int*)d_in[1];
    const int*   edges     = (const int*)d_in[2];
    const float* efeat     = (const float*)d_in[3];
    const float* embed     = (const float*)d_in[5];
    const float* me_w1 = (const float*)d_in[6],  *me_b1 = (const float*)d_in[7];
    const float* me_w2 = (const float*)d_in[8],  *me_b2 = (const float*)d_in[9];
    const float* mn_w1 = (const float*)d_in[10], *mn_b1 = (const float*)d_in[11];
    const float* mn_w2 = (const float*)d_in[12], *mn_b2 = (const float*)d_in[13];
    const float* st_w1 = (const float*)d_in[14], *st_b1 = (const float*)d_in[15];
    const float* st_w2 = (const float*)d_in[16], *st_b2 = (const float*)d_in[17];
    const float* ro_w1 = (const float*)d_in[18], *ro_b1 = (const float*)d_in[19];
    const float* ro_w2 = (const float*)d_in[20], *ro_b2 = (const float*)d_in[21];
    const float* ev_w  = (const float*)d_in[22], *ev_b  = (const float*)d_in[23];

    char* ws = (char*)d_ws;
    int* off   = (int*)(ws + O_OFF);
    int* gsrc  = (int*)(ws + O_GSRC);
    int* gdst  = (int*)(ws + O_GDST);
    int* cnt   = (int*)(ws + O_CNT);
    int* coff  = (int*)(ws + O_COFF);
    int* pos   = (int*)(ws + O_POS);
    int* eidl  = (int*)(ws + O_EIDL);
    int* gsrcs = (int*)(ws + O_GSRCS);
    unsigned short* erbf  = (unsigned short*)(ws + O_ERBF);
    unsigned short* me1T  = (unsigned short*)(ws + O_ME1T);
    unsigned short* me2T  = (unsigned short*)(ws + O_ME2T);
    unsigned short* mn1T  = (unsigned short*)(ws + O_MN1T);
    unsigned short* mn2T  = (unsigned short*)(ws + O_MN2T);
    unsigned short* st1T  = (unsigned short*)(ws + O_ST1T);
    unsigned short* st2T  = (unsigned short*)(ws + O_ST2T);
    unsigned short* ro1T  = (unsigned short*)(ws + O_RO1T);
    float*          x     = (float*)(ws + O_X);
    unsigned short* xb    = (unsigned short*)(ws + O_XB);
    unsigned short* tmpb  = (unsigned short*)(ws + O_TMPB);
    unsigned short* nmsgb = (unsigned short*)(ws + O_NMSG);
    unsigned short* msum  = (unsigned short*)(ws + O_MSUM);
    unsigned short* gate  = (unsigned short*)(ws + O_GATE);
    float* out = (float*)d_out;

    hipMemsetAsync(cnt, 0, TN * 4, stream);
    k_offsets<<<1, Bb, 0, stream>>>(num_nodes, off);
    k_edgeprep<<<TE / 256, 256, 0, stream>>>(edges, off, gsrc, gdst, cnt);
    k_scan<<<1, 1024, 0, stream>>>(cnt, coff, pos);
    k_fill<<<TE / 256, 256, 0, stream>>>(gdst, gsrc, pos, eidl, gsrcs);
    k_rbf<<<(TE * EKPAD) / 256, 256, 0, stream>>>(efeat, erbf);
    k_embed<<<TN, 256, 0, stream>>>(nodes, embed, x, xb);
    {
        const int total = Ll * 256 * EKPAD + 5 * Ll * 256 * 256 + 256 * 256;
        k_wprep<<<total / 256, 256, 0, stream>>>(me_w1, me_w2, mn_w1, mn_w2, st_w1, st_w2, ro_w1,
                                                 me1T, me2T, mn1T, mn2T, st1T, st2T, ro1T);
    }

    for (int i = 0; i < Ll; ++i) {
        fused_mlp<EKPAD, 0><<<TE / 128, 256, 0, stream>>>(
            erbf, me1T + i * 256 * EKPAD, me_b1 + i * 256,
            me2T + i * 65536, me_b2 + i * 256, gate, nullptr, nullptr);
        fused_mlp<256, 0><<<TN / 128, 256, 0, stream>>>(
            xb, mn1T + i * 65536, mn_b1 + i * 256,
            mn2T + i * 65536, mn_b2 + i * 256, nmsgb, nullptr, nullptr);
        k_agg<<<TN, 256, 0, stream>>>(nmsgb, gate, coff, gsrcs, eidl, msum);
        fused_mlp<256, 2><<<TN / 128, 256, 0, stream>>>(
            msum, st1T + i * 65536, st_b1 + i * 256,
            st2T + i * 65536, st_b2 + i * 256, nullptr, x, xb);
    }

    const dim3 gN(2, TN / 64), blk(256);
    gemm_k<1, 0, 64><<<gN, blk, 0, stream>>>(xb, ro1T, ro_b1, tmpb, nullptr, nullptr, TN, 256, 256);
    k_readout<<<Bb, 256, 0, stream>>>(tmpb, ro_w2, ro_b2, num_nodes, ev_w, ev_b, out);
}

// Round 4
// 879.176 us; speedup vs baseline: 2.5084x; 2.5084x over previous
//
#include <hip/hip_runtime.h>

#define Bb 64
#define Nn 128
#define Ee 2048
#define Hh 256
#define Ll 6
#define TN 8192
#define TE 131072
#define EDGE 50
#define EKPAD 64

typedef __attribute__((ext_vector_type(4))) float f32x4;
typedef __attribute__((ext_vector_type(8))) __bf16 bf16x8;
typedef __attribute__((ext_vector_type(8))) unsigned short ushort8;

__device__ inline float b2f(unsigned short u) {
    union { unsigned u; float f; } v; v.u = ((unsigned)u) << 16; return v.f;
}
__device__ inline unsigned short f2b(float f) {
    union { float f; unsigned u; } v; v.f = f;
    unsigned r = v.u + 0x7fffu + ((v.u >> 16) & 1u);
    return (unsigned short)(r >> 16);
}
__device__ inline float spf(float x) {
    return fmaxf(x, 0.f) + __logf(1.f + __expf(-fabsf(x)));
}
__device__ inline float sspf(float x) {
    return spf(x) - 0.69314718055994530942f;
}

// GEMM: C = act(A @ WT^T + bias), N fixed 256. Swapped-MFMA epilogue:
// lane holds 4 consecutive cols -> 8B LDS packs -> linear 16B/lane stores.
template <int ACT, int OUTMODE, int TM>
__global__ __launch_bounds__(256)
void gemm_k(const unsigned short* __restrict__ A,
            const unsigned short* __restrict__ WT,
            const float* __restrict__ bias,
            unsigned short* __restrict__ Cb,
            float* __restrict__ Xf,
            unsigned short* __restrict__ Xb,
            int M, int K)
{
    constexpr int BK  = 64;
    constexpr int TNc = 128;
    constexpr int MR  = TM / 32;
    constexpr int NR  = 4;
    constexpr int STAGE_B = (TM + TNc) * BK * 2;
    constexpr int EPI_B   = (OUTMODE == 2) ? TM * TNc * 4 : TM * TNc * 2;
    constexpr int SMEM_B  = STAGE_B > EPI_B ? STAGE_B : EPI_B;

    __shared__ __align__(16) unsigned char smem[SMEM_B];
    unsigned short* As = (unsigned short*)smem;
    unsigned short* Bs = As + TM * BK;

    const int tid  = threadIdx.x;
    const int lane = tid & 63;
    const int w    = tid >> 6;
    const int wr   = w >> 1, wc = w & 1;
    const int r16  = lane & 15;
    const int kg   = lane >> 4;

    const long brow = (long)blockIdx.y * TM;
    const int  bcol = blockIdx.x * TNc;

    constexpr int ACH = TM / 8;
    constexpr int NCH = ACH + TNc / 8;
    constexpr int IPW = NCH / 4;
    const int lrow  = lane >> 3;
    const int lslot = lane & 7;

    f32x4 acc[MR][NR];
#pragma unroll
    for (int m = 0; m < MR; ++m)
#pragma unroll
        for (int n = 0; n < NR; ++n) acc[m][n] = f32x4{0.f, 0.f, 0.f, 0.f};

    for (int k0 = 0; k0 < K; k0 += BK) {
        __syncthreads();
#pragma unroll
        for (int i = 0; i < IPW; ++i) {
            const int c    = w * IPW + i;
            const bool isA = c < ACH;
            const int cc   = isA ? c : c - ACH;
            const int srow = cc * 8 + lrow;
            const int kch  = lslot ^ (srow & 7);
            const unsigned short* gp = isA
                ? A  + (brow + srow) * (long)K + k0 + kch * 8
                : WT + (bcol + srow) * (long)K + k0 + kch * 8;
            unsigned short* lp = (isA ? As : Bs) + cc * 512;
            __builtin_amdgcn_global_load_lds(
                (const __attribute__((address_space(1))) void*)gp,
                (__attribute__((address_space(3))) void*)lp, 16, 0, 0);
        }
        __syncthreads();

        bf16x8 a[MR][2], b[NR][2];
#pragma unroll
        for (int m = 0; m < MR; ++m) {
            const int row = wr * (MR * 16) + m * 16 + r16;
            const unsigned short* base = As + row * BK;
#pragma unroll
            for (int kk = 0; kk < 2; ++kk) {
                const int slot = (kk * 4 + kg) ^ (row & 7);
                a[m][kk] = *(const bf16x8*)(base + slot * 8);
            }
        }
#pragma unroll
        for (int n = 0; n < NR; ++n) {
            const int row = wc * 64 + n * 16 + r16;
            const unsigned short* base = Bs + row * BK;
#pragma unroll
            for (int kk = 0; kk < 2; ++kk) {
                const int slot = (kk * 4 + kg) ^ (row & 7);
                b[n][kk] = *(const bf16x8*)(base + slot * 8);
            }
        }
#pragma unroll
        for (int kk = 0; kk < 2; ++kk)
#pragma unroll
            for (int m = 0; m < MR; ++m)
#pragma unroll
                for (int n = 0; n < NR; ++n)
                    acc[m][n] = __builtin_amdgcn_mfma_f32_16x16x32_bf16(
                        b[n][kk], a[m][kk], acc[m][n], 0, 0, 0);
    }

    __syncthreads();

    if (OUTMODE != 2) {
#pragma unroll
        for (int m = 0; m < MR; ++m) {
            const int row = wr * (MR * 16) + m * 16 + r16;
#pragma unroll
            for (int n = 0; n < NR; ++n) {
                const int colL = wc * 64 + n * 16 + kg * 4;
                const f32x4 bv = *(const f32x4*)(bias + bcol + colL);
                float v0 = acc[m][n][0] + bv[0];
                float v1 = acc[m][n][1] + bv[1];
                float v2 = acc[m][n][2] + bv[2];
                float v3 = acc[m][n][3] + bv[3];
                if (ACT) { v0 = sspf(v0); v1 = sspf(v1); v2 = sspf(v2); v3 = sspf(v3); }
                uint2 p;
                p.x = (unsigned)f2b(v0) | ((unsigned)f2b(v1) << 16);
                p.y = (unsigned)f2b(v2) | ((unsigned)f2b(v3) << 16);
                const int off = (row * 256 + colL * 2) ^ ((row & 7) << 4);
                *(uint2*)(smem + off) = p;
            }
        }
        __syncthreads();
        constexpr int ITER = TM / 16;
#pragma unroll
        for (int q = 0; q < ITER; ++q) {
            const int flat = q * 4096 + tid * 16;
            const int row = flat >> 8, cbyte = flat & 255;
            uint4 d = *(const uint4*)(smem + ((row * 256 + cbyte) ^ ((row & 7) << 4)));
            *(uint4*)((unsigned char*)Cb + (brow + row) * 512 + bcol * 2 + cbyte) = d;
        }
    } else {
#pragma unroll
        for (int m = 0; m < MR; ++m) {
            const int row = wr * (MR * 16) + m * 16 + r16;
#pragma unroll
            for (int n = 0; n < NR; ++n) {
                const int colL = wc * 64 + n * 16 + kg * 4;
                const f32x4 bv = *(const f32x4*)(bias + bcol + colL);
                f32x4 v = acc[m][n] + bv;
                const int off = (row * 512 + colL * 4) ^ ((row & 7) << 4);
                *(f32x4*)(smem + off) = v;
            }
        }
        __syncthreads();
        constexpr int ITER = TM / 8;
#pragma unroll
        for (int q = 0; q < ITER; ++q) {
            const int flat = q * 4096 + tid * 16;
            const int row = flat >> 9, cbyte = flat & 511;
            f32x4 v = *(const f32x4*)(smem + ((row * 512 + cbyte) ^ ((row & 7) << 4)));
            const long base = (brow + row) * 256 + bcol + (cbyte >> 2);
            f32x4 xo = *(const f32x4*)(Xf + base);
            f32x4 nx = xo + v;
            *(f32x4*)(Xf + base) = nx;
            uint2 p;
            p.x = (unsigned)f2b(nx[0]) | ((unsigned)f2b(nx[1]) << 16);
            p.y = (unsigned)f2b(nx[2]) | ((unsigned)f2b(nx[3]) << 16);
            *(uint2*)(Xb + base) = p;
        }
    }
}

__global__ void k_offsets(const int* __restrict__ num_nodes, int* __restrict__ off) {
    __shared__ int s[Bb];
    int t = threadIdx.x;
    s[t] = num_nodes[t];
    __syncthreads();
    for (int d = 1; d < Bb; d <<= 1) {
        int v = (t >= d) ? s[t - d] : 0;
        __syncthreads();
        s[t] += v;
        __syncthreads();
    }
    off[t + 1] = s[t];
    if (t == 0) off[0] = 0;
}

__global__ void k_edgeprep(const int* __restrict__ edges, const int* __restrict__ off,
                           int* __restrict__ gsrc, int* __restrict__ gdst, int* __restrict__ cnt) {
    int ge = blockIdx.x * 256 + threadIdx.x;
    if (ge >= TE) return;
    int b = ge >> 11;
    int o = off[b];
    gsrc[ge] = edges[ge * 2 + 0] + o;
    int d = edges[ge * 2 + 1] + o;
    gdst[ge] = d;
    atomicAdd(&cnt[d], 1);
}

__global__ void k_scan(const int* __restrict__ cnt, int* __restrict__ coff, int* __restrict__ pos) {
    __shared__ int part[1024];
    int t = threadIdx.x;
    int loc[8];
    int s = 0;
#pragma unroll
    for (int j = 0; j < 8; ++j) { loc[j] = cnt[t * 8 + j]; s += loc[j]; }
    part[t] = s;
    __syncthreads();
    for (int d = 1; d < 1024; d <<= 1) {
        int v = (t >= d) ? part[t - d] : 0;
        __syncthreads();
        part[t] += v;
        __syncthreads();
    }
    int base = part[t] - s;
#pragma unroll
    for (int j = 0; j < 8; ++j) {
        int idx = t * 8 + j;
        coff[idx] = base;
        pos[idx]  = base;
        base += loc[j];
    }
    if (t == 1023) coff[TN] = part[1023];
}

__global__ void k_fill(const int* __restrict__ gdst, const int* __restrict__ gsrc,
                       int* __restrict__ pos, int* __restrict__ eidl, int* __restrict__ gsrcs) {
    int ge = blockIdx.x * 256 + threadIdx.x;
    if (ge >= TE) return;
    int p = atomicAdd(&pos[gdst[ge]], 1);
    eidl[p]  = ge;
    gsrcs[p] = gsrc[ge];
}

__global__ void k_rbf(const float* __restrict__ ef, unsigned short* __restrict__ erbf) {
    int gid = blockIdx.x * 256 + threadIdx.x;
    int ge = gid >> 6, k = gid & 63;
    float v = 0.f;
    if (k < EDGE) {
        float d = ef[ge];
        float t = d - 0.1f * (float)k;
        v = __expf(-50.f * t * t);
    }
    erbf[gid] = f2b(v);
}

__global__ void k_embed(const int* __restrict__ nodes, const float* __restrict__ embed,
                        float* __restrict__ x, unsigned short* __restrict__ xb) {
    int gid = blockIdx.x * 256 + threadIdx.x;
    int i = gid >> 8, c = gid & 255;
    float v = embed[(nodes[i] << 8) + c];
    x[gid] = v;
    xb[gid] = f2b(v);
}

__global__ void k_wprep(const float* __restrict__ me_w1, const float* __restrict__ me_w2,
                        const float* __restrict__ mn_w1, const float* __restrict__ mn_w2,
                        const float* __restrict__ st_w1, const float* __restrict__ st_w2,
                        const float* __restrict__ ro_w1,
                        unsigned short* __restrict__ me1T, unsigned short* __restrict__ me2T,
                        unsigned short* __restrict__ mn1T, unsigned short* __restrict__ mn2T,
                        unsigned short* __restrict__ st1T, unsigned short* __restrict__ st2T,
                        unsigned short* __restrict__ ro1T) {
    int gid = blockIdx.x * 256 + threadIdx.x;
    const int S1 = Ll * 256 * EKPAD;
    if (gid < S1) {
        int i = gid / (256 * EKPAD);
        int r = gid % (256 * EKPAD);
        int n = r / EKPAD, k = r % EKPAD;
        float v = (k < EDGE) ? me_w1[(i * EDGE + k) * 256 + n] : 0.f;
        me1T[gid] = f2b(v);
        return;
    }
    gid -= S1;
    const int S2 = Ll * 256 * 256;
    const float* srcs[5] = { me_w2, mn_w1, mn_w2, st_w1, st_w2 };
    unsigned short* dsts[5] = { me2T, mn1T, mn2T, st1T, st2T };
#pragma unroll
    for (int q = 0; q < 5; ++q) {
        if (gid < S2) {
            int i = gid >> 16;
            int r = gid & 65535;
            int n = r >> 8, k = r & 255;
            dsts[q][gid] = f2b(srcs[q][(i << 16) + k * 256 + n]);
            return;
        }
        gid -= S2;
    }
    int n = gid >> 8, k = gid & 255;
    ro1T[gid] = f2b(ro_w1[k * 256 + n]);
}

__global__ void k_agg(const unsigned short* __restrict__ nmsgb, const unsigned short* __restrict__ gates,
                      const int* __restrict__ coff, const int* __restrict__ gsrcs,
                      const int* __restrict__ eidl, unsigned short* __restrict__ msum) {
    int tid = threadIdx.x;
    int which = tid >> 5, local = tid & 31;
    int n = blockIdx.x * 8 + which;
    int c0 = local * 8;
    float s0 = 0.f, s1 = 0.f, s2 = 0.f, s3 = 0.f, s4 = 0.f, s5 = 0.f, s6 = 0.f, s7 = 0.f;
    int beg = coff[n], end = coff[n + 1];
    for (int i = beg; i < end; ++i) {
        int e  = eidl[i];
        int sr = gsrcs[i];
        ushort8 nv = *(const ushort8*)(nmsgb + ((long)sr << 8) + c0);
        ushort8 gv = *(const ushort8*)(gates + ((long)e << 8) + c0);
        s0 += b2f(nv[0]) * b2f(gv[0]);
        s1 += b2f(nv[1]) * b2f(gv[1]);
        s2 += b2f(nv[2]) * b2f(gv[2]);
        s3 += b2f(nv[3]) * b2f(gv[3]);
        s4 += b2f(nv[4]) * b2f(gv[4]);
        s5 += b2f(nv[5]) * b2f(gv[5]);
        s6 += b2f(nv[6]) * b2f(gv[6]);
        s7 += b2f(nv[7]) * b2f(gv[7]);
    }
    ushort8 o;
    o[0] = f2b(s0); o[1] = f2b(s1); o[2] = f2b(s2); o[3] = f2b(s3);
    o[4] = f2b(s4); o[5] = f2b(s5); o[6] = f2b(s6); o[7] = f2b(s7);
    *(ushort8*)(msum + ((long)n << 8) + c0) = o;
}

__global__ void k_readout(const unsigned short* __restrict__ t, const float* __restrict__ w2,
                          const float* __restrict__ b2, const int* __restrict__ num_nodes,
                          const float* __restrict__ evw, const float* __restrict__ evb,
                          float* __restrict__ out) {
    __shared__ float red[256];
    int b = blockIdx.x, tid = threadIdx.x;
    const unsigned short* tb = t + (long)b * Nn * 256;
    float part = 0.f;
    for (int i = tid; i < Nn * 256; i += 256)
        part += b2f(tb[i]) * w2[i & 255];
    red[tid] = part;
    __syncthreads();
    for (int d = 128; d > 0; d >>= 1) {
        if (tid < d) red[tid] += red[tid + d];
        __syncthreads();
    }
    if (tid == 0) {
        float g = red[0] + (float)Nn * b2[0];
        g = g * 2.0f + (-1.5f) * (float)num_nodes[b];
        out[b * 4 + 0] = g * evw[0] + evb[0];
        out[b * 4 + 1] = spf(g * evw[1] + evb[1]);
        out[b * 4 + 2] = spf(g * evw[2] + evb[2]) + 1.f;
        out[b * 4 + 3] = spf(g * evw[3] + evb[3]);
    }
}

constexpr size_t al(size_t x) { return (x + 255) & ~(size_t)255; }
constexpr size_t O_OFF   = 0;
constexpr size_t O_GSRC  = al(O_OFF + 65 * 4);
constexpr size_t O_GDST  = al(O_GSRC + (size_t)TE * 4);
constexpr size_t O_CNT   = al(O_GDST + (size_t)TE * 4);
constexpr size_t O_COFF  = al(O_CNT + (size_t)TN * 4);
constexpr size_t O_POS   = al(O_COFF + (size_t)(TN + 1) * 4);
constexpr size_t O_EIDL  = al(O_POS + (size_t)TN * 4);
constexpr size_t O_GSRCS = al(O_EIDL + (size_t)TE * 4);
constexpr size_t O_ERBF  = al(O_GSRCS + (size_t)TE * 4);
constexpr size_t O_ME1T  = al(O_ERBF + (size_t)TE * EKPAD * 2);
constexpr size_t O_ME2T  = al(O_ME1T + (size_t)Ll * 256 * EKPAD * 2);
constexpr size_t O_MN1T  = al(O_ME2T + (size_t)Ll * 256 * 256 * 2);
constexpr size_t O_MN2T  = al(O_MN1T + (size_t)Ll * 256 * 256 * 2);
constexpr size_t O_ST1T  = al(O_MN2T + (size_t)Ll * 256 * 256 * 2);
constexpr size_t O_ST2T  = al(O_ST1T + (size_t)Ll * 256 * 256 * 2);
constexpr size_t O_RO1T  = al(O_ST2T + (size_t)Ll * 256 * 256 * 2);
constexpr size_t O_X     = al(O_RO1T + (size_t)256 * 256 * 2);
constexpr size_t O_XB    = al(O_X + (size_t)TN * 256 * 4);
constexpr size_t O_TMPB  = al(O_XB + (size_t)TN * 256 * 2);
constexpr size_t O_NMSG  = al(O_TMPB + (size_t)TN * 256 * 2);
constexpr size_t O_MSUM  = al(O_NMSG + (size_t)TN * 256 * 2);
constexpr size_t O_TEDG  = al(O_MSUM + (size_t)TN * 256 * 2);
constexpr size_t O_GATE  = al(O_TEDG + (size_t)TE * 256 * 2);
constexpr size_t WS_NEED = al(O_GATE + (size_t)TE * 256 * 2);

extern "C" void kernel_launch(void* const* d_in, const int* in_sizes, int n_in,
                              void* d_out, int out_size, void* d_ws, size_t ws_size,
                              hipStream_t stream) {
    if (ws_size < WS_NEED) return;

    const int*   nodes     = (const int*)d_in[0];
    const int*   num_nodes = (const int*)d_in[1];
    const int*   edges     = (const int*)d_in[2];
    const float* efeat     = (const float*)d_in[3];
    const float* embed     = (const float*)d_in[5];
    const float* me_w1 = (const float*)d_in[6],  *me_b1 = (const float*)d_in[7];
    const float* me_w2 = (const float*)d_in[8],  *me_b2 = (const float*)d_in[9];
    const float* mn_w1 = (const float*)d_in[10], *mn_b1 = (const float*)d_in[11];
    const float* mn_w2 = (const float*)d_in[12], *mn_b2 = (const float*)d_in[13];
    const float* st_w1 = (const float*)d_in[14], *st_b1 = (const float*)d_in[15];
    const float* st_w2 = (const float*)d_in[16], *st_b2 = (const float*)d_in[17];
    const float* ro_w1 = (const float*)d_in[18], *ro_b1 = (const float*)d_in[19];
    const float* ro_w2 = (const float*)d_in[20], *ro_b2 = (const float*)d_in[21];
    const float* ev_w  = (const float*)d_in[22], *ev_b  = (const float*)d_in[23];

    char* ws = (char*)d_ws;
    int* off   = (int*)(ws + O_OFF);
    int* gsrc  = (int*)(ws + O_GSRC);
    int* gdst  = (int*)(ws + O_GDST);
    int* cnt   = (int*)(ws + O_CNT);
    int* coff  = (int*)(ws + O_COFF);
    int* pos   = (int*)(ws + O_POS);
    int* eidl  = (int*)(ws + O_EIDL);
    int* gsrcs = (int*)(ws + O_GSRCS);
    unsigned short* erbf  = (unsigned short*)(ws + O_ERBF);
    unsigned short* me1T  = (unsigned short*)(ws + O_ME1T);
    unsigned short* me2T  = (unsigned short*)(ws + O_ME2T);
    unsigned short* mn1T  = (unsigned short*)(ws + O_MN1T);
    unsigned short* mn2T  = (unsigned short*)(ws + O_MN2T);
    unsigned short* st1T  = (unsigned short*)(ws + O_ST1T);
    unsigned short* st2T  = (unsigned short*)(ws + O_ST2T);
    unsigned short* ro1T  = (unsigned short*)(ws + O_RO1T);
    float*          x     = (float*)(ws + O_X);
    unsigned short* xb    = (unsigned short*)(ws + O_XB);
    unsigned short* tmpb  = (unsigned short*)(ws + O_TMPB);
    unsigned short* nmsgb = (unsigned short*)(ws + O_NMSG);
    unsigned short* msum  = (unsigned short*)(ws + O_MSUM);
    unsigned short* tedg  = (unsigned short*)(ws + O_TEDG);
    unsigned short* gate  = (unsigned short*)(ws + O_GATE);
    float* out = (float*)d_out;

    hipMemsetAsync(cnt, 0, TN * 4, stream);
    k_offsets<<<1, Bb, 0, stream>>>(num_nodes, off);
    k_edgeprep<<<TE / 256, 256, 0, stream>>>(edges, off, gsrc, gdst, cnt);
    k_scan<<<1, 1024, 0, stream>>>(cnt, coff, pos);
    k_fill<<<TE / 256, 256, 0, stream>>>(gdst, gsrc, pos, eidl, gsrcs);
    k_rbf<<<(TE * EKPAD) / 256, 256, 0, stream>>>(efeat, erbf);
    k_embed<<<TN, 256, 0, stream>>>(nodes, embed, x, xb);
    {
        const int total = Ll * 256 * EKPAD + 5 * Ll * 256 * 256 + 256 * 256;
        k_wprep<<<total / 256, 256, 0, stream>>>(me_w1, me_w2, mn_w1, mn_w2, st_w1, st_w2, ro_w1,
                                                 me1T, me2T, mn1T, mn2T, st1T, st2T, ro1T);
    }

    const dim3 gE(2, TE / 128), gN(2, TN / 64), blk(256);
    for (int i = 0; i < Ll; ++i) {
        gemm_k<1, 0, 128><<<gE, blk, 0, stream>>>(erbf, me1T + i * 256 * EKPAD, me_b1 + i * 256,
                                                  tedg, nullptr, nullptr, TE, EKPAD);
        gemm_k<0, 0, 128><<<gE, blk, 0, stream>>>(tedg, me2T + i * 65536, me_b2 + i * 256,
                                                  gate, nullptr, nullptr, TE, 256);
        gemm_k<1, 0, 64><<<gN, blk, 0, stream>>>(xb, mn1T + i * 65536, mn_b1 + i * 256,
                                                 tmpb, nullptr, nullptr, TN, 256);
        gemm_k<0, 0, 64><<<gN, blk, 0, stream>>>(tmpb, mn2T + i * 65536, mn_b2 + i * 256,
                                                 nmsgb, nullptr, nullptr, TN, 256);
        k_agg<<<TN / 8, 256, 0, stream>>>(nmsgb, gate, coff, gsrcs, eidl, msum);
        gemm_k<1, 0, 64><<<gN, blk, 0, stream>>>(msum, st1T + i * 65536, st_b1 + i * 256,
                                                 tmpb, nullptr, nullptr, TN, 256);
        gemm_k<0, 2, 64><<<gN, blk, 0, stream>>>(tmpb, st2T + i * 65536, st_b2 + i * 256,
                                                 nullptr, x, xb, TN, 256);
    }

    gemm_k<1, 0, 64><<<gN, blk, 0, stream>>>(xb, ro1T, ro_b1, tmpb, nullptr, nullptr, TN, 256);
    k_readout<<<Bb, 256, 0, stream>>>(tmpb, ro_w2, ro_b2, num_nodes, ev_w, ev_b, out);
}